// Round 7
// baseline (346.227 us; speedup 1.0000x reference)
//
#include <hip/hip_runtime.h>

#define NN 50000
#define NE 800000
#define NHB 3125   // = NE/256 = NN/16 exactly (no bounds checks needed)
// inputs: node_features[NN*64] f32, edge_features[NE*32] f32, src[NE] i32,
//         dst[NE] i32, w_group[160] f32, w_srcattn[96] f32, w_lin[160*64] f32
// out: [NN*64] f32
//
// Algebra: a = au[e].x + p1[src] + p2[dst]; t = p3[src]; u = au[e].y
//          gamma = e^a / den_src[src]; s = t + gamma*u
// dst-CSR via hist(rank)+assign; dst-softmax denom = inline segment sum.

typedef __attribute__((ext_vector_type(8))) short bf16x8;  // 8 bf16 (4 VGPRs)
typedef __attribute__((ext_vector_type(4))) float f32x4;

static __device__ __forceinline__ short f2bf(float f) {
    unsigned int u = __float_as_uint(f);
    u += 0x7FFFu + ((u >> 16) & 1u);       // round-to-nearest-even
    return (short)(u >> 16);
}

// ---------------------------------------------------------------------------
// Pass 0 (3-way fused, disjoint block ranges):
//  [0,NHB):      dst histogram + per-edge rank (atomic return -> 4B store)
//  [NHB,2NHB):   per-node projections p1 = h·wg[32:96], pd = h·wg[96:160],
//                dp[n].y = h·wa[0:64]  (16 lanes/node, shfl reduce)
//  [2NHB,3NHB):  per-edge ef dots au[e] = {ef·wg[0:32], ef·wa[64:96]}
// The streaming efdot phase overlaps the latency-bound hist phase.
// ---------------------------------------------------------------------------
__global__ __launch_bounds__(256) void k_pre(
    const float* __restrict__ h, const float* __restrict__ ef,
    const int* __restrict__ dst,
    const float* __restrict__ wg, const float* __restrict__ wa,
    int* __restrict__ cnt, int* __restrict__ rank,
    float* __restrict__ p1, float* __restrict__ pd, float* __restrict__ dpf,
    float2* __restrict__ au)
{
    int tid = threadIdx.x;
    if (blockIdx.x < NHB) {                       // ---- hist ----
        int e = blockIdx.x * 256 + tid;
        rank[e] = atomicAdd(&cnt[dst[e]], 1);
        return;
    }
    if (blockIdx.x < 2 * NHB) {                   // ---- proj ----
        __shared__ float4 ls[16], ld[16], lt[16];
        if (tid < 16)      ls[tid]      = ((const float4*)wg)[8 + tid];   // wg[32:96)
        else if (tid < 32) ld[tid - 16] = ((const float4*)wg)[8 + tid];   // wg[96:160)
        else if (tid < 48) lt[tid - 32] = ((const float4*)wa)[tid - 32];  // wa[0:64)
        __syncthreads();
        int n = (blockIdx.x - NHB) * 16 + (tid >> 4);
        int l16 = tid & 15;
        float4 v = ((const float4*)(h + (size_t)n * 64))[l16];
        float4 w1 = ls[l16], w2 = ld[l16], w3 = lt[l16];
        float s1 = v.x*w1.x + v.y*w1.y + v.z*w1.z + v.w*w1.w;
        float s2 = v.x*w2.x + v.y*w2.y + v.z*w2.z + v.w*w2.w;
        float s3 = v.x*w3.x + v.y*w3.y + v.z*w3.z + v.w*w3.w;
        #pragma unroll
        for (int m = 8; m; m >>= 1) {
            s1 += __shfl_xor(s1, m);
            s2 += __shfl_xor(s2, m);
            s3 += __shfl_xor(s3, m);
        }
        if (l16 == 0) { p1[n] = s1; pd[n] = s2; dpf[2 * n + 1] = s3; }
        return;
    }
    // ---- efdot ----
    __shared__ float4 lwe[8], lae[8];
    if (tid < 8)       lwe[tid]     = ((const float4*)wg)[tid];          // wg[0:32)
    else if (tid < 16) lae[tid - 8] = ((const float4*)wa)[tid - 8 + 16]; // wa[64:96)
    __syncthreads();
    int e = (blockIdx.x - 2 * NHB) * 256 + tid;
    const float4* e4 = (const float4*)(ef + (size_t)e * 32);
    float a = 0.f, u = 0.f;
    #pragma unroll
    for (int q = 0; q < 8; ++q) {
        float4 v = e4[q], w = lwe[q], w2 = lae[q];
        a += v.x*w.x  + v.y*w.y  + v.z*w.z  + v.w*w.w;
        u += v.x*w2.x + v.y*w2.y + v.z*w2.z + v.w*w2.w;
    }
    au[e] = make_float2(a, u);
}

// ---------------------------------------------------------------------------
// Pass 1: contiguous (order-arbitrary) segment bases from cnt.
// ---------------------------------------------------------------------------
__global__ __launch_bounds__(256) void k_assign(
    const int* __restrict__ cnt, int* __restrict__ off, int* __restrict__ gtotal)
{
    int n = blockIdx.x * 256 + threadIdx.x;
    int lane = threadIdx.x & 63;
    int c = (n < NN) ? cnt[n] : 0;
    int pre = c;
    #pragma unroll
    for (int d = 1; d < 64; d <<= 1) {
        int v = __shfl_up(pre, d);
        if (lane >= d) pre += v;
    }
    int base = 0;
    if (lane == 63) base = atomicAdd(gtotal, pre);
    base = __shfl(base, 63);
    if (n < NN) off[n] = base + pre - c;
}

// ---------------------------------------------------------------------------
// Pass 2: slim per-edge scoring + CSR routing. All heavy streaming is gone:
// coalesced au/src/dst/rank loads + 3 small L2-resident gathers + 1 atomic
// (fire-and-forget) + 1 16B scatter store.
// recA[pos] = {src, e, e^a, u}
// ---------------------------------------------------------------------------
__global__ __launch_bounds__(256) void k_edge(
    const float2* __restrict__ au, const int* __restrict__ src,
    const int* __restrict__ dst, const int* __restrict__ rank,
    const float* __restrict__ p1, const float* __restrict__ pd,
    float* __restrict__ dpf, const int* __restrict__ off,
    int4* __restrict__ recA)
{
    int e = blockIdx.x * 256 + threadIdx.x;
    int s = src[e], d = dst[e], rk = rank[e];
    float2 ad = au[e];
    float a = ad.x + p1[s] + pd[d];
    float eav = __expf(a);
    atomicAdd(&dpf[2 * s], eav);           // den_src; no return needed
    int pos = off[d] + rk;
    recA[pos] = make_int4(s, e, __float_as_int(eav), __float_as_int(ad.y));
}

// ---------------------------------------------------------------------------
// Pass 3: linear streaming rewrite: rec.z = es = exp(p3 + gamma*u),
// rec.w = es*gamma. Removes dp-gather/div/exp from k_reduce's critical loop.
// ---------------------------------------------------------------------------
__global__ __launch_bounds__(256) void k_rewrite(
    const float2* __restrict__ dp, int4* __restrict__ recA)
{
    int pos = blockIdx.x * 256 + threadIdx.x;
    int4 r = recA[pos];
    float2 dt = dp[r.x];                   // {den_src, p3}
    float g = __int_as_float(r.z) / dt.x;
    float es = __expf(dt.y + g * __int_as_float(r.w));
    r.z = __float_as_int(es);
    r.w = __float_as_int(es * g);
    recA[pos] = r;
}

// ---------------------------------------------------------------------------
// Pass 4: wave-per-node segmented softmax-reduce, 4-way unrolled.
// Iteration is now: rec load -> {h, ef} gathers -> FMA (shortest chain).
// ef rows: two records per wave-wide load (lanes>=32 take the odd record).
// ---------------------------------------------------------------------------
__global__ __launch_bounds__(256) void k_reduce(
    const float* __restrict__ h, const float* __restrict__ ef,
    const int* __restrict__ cnt, const int* __restrict__ off,
    const int4* __restrict__ recA, float* __restrict__ accum)
{
    int n = blockIdx.x * 4 + (threadIdx.x >> 6);
    int lane = threadIdx.x & 63;
    bool up = lane >= 32;
    int l5 = lane & 31;
    int deg = cnt[n], base = off[n];
    float acch = 0.f, acce = 0.f, den = 0.f;
    int j = 0;
    for (; j + 4 <= deg; j += 4) {
        int4 r0 = recA[base+j+0], r1 = recA[base+j+1];
        int4 r2 = recA[base+j+2], r3 = recA[base+j+3];
        float h0 = h[(size_t)r0.x*64+lane], h1 = h[(size_t)r1.x*64+lane];
        float h2 = h[(size_t)r2.x*64+lane], h3 = h[(size_t)r3.x*64+lane];
        int eA = up ? r1.y : r0.y, eB = up ? r3.y : r2.y;
        float efA = ef[(size_t)eA*32 + l5];
        float efB = ef[(size_t)eB*32 + l5];
        float s0 = __int_as_float(r0.z), s1 = __int_as_float(r1.z);
        float s2 = __int_as_float(r2.z), s3 = __int_as_float(r3.z);
        den  += s0 + s1 + s2 + s3;
        acch += s0*h0 + s1*h1 + s2*h2 + s3*h3;
        float wA = up ? __int_as_float(r1.w) : __int_as_float(r0.w);
        float wB = up ? __int_as_float(r3.w) : __int_as_float(r2.w);
        acce += wA*efA + wB*efB;
    }
    for (; j < deg; ++j) {
        int4 r = recA[base+j];
        float s = __int_as_float(r.z);
        den += s;
        acch += s * h[(size_t)r.x*64+lane];
        if (!up) acce += __int_as_float(r.w) * ef[(size_t)r.y*32 + l5];
    }
    acce += __shfl_xor(acce, 32);          // fold odd-record (upper-lane) part
    float inv = (deg > 0) ? 1.f/den : 0.f;
    accum[(size_t)n*96 + lane] = acch * inv;
    if (!up) accum[(size_t)n*96 + 64 + lane] = acce * inv;
}

// ---------------------------------------------------------------------------
// Pass 5: out = relu(concat([h, accum]) @ w_lin) as an MFMA bf16 GEMM.
// [NN x 160] · [160 x 64]; w_lin held in registers (20 B-fragments/wave),
// 16-node M-tiles grid-strided. No LDS.
// Layouts (m89/m120-verified): A[m=lane&15][k=quad*8+j],
// B[k=quad*8+j][n=lane&15], D[row=quad*4+reg][col=lane&15].
// ---------------------------------------------------------------------------
__global__ __launch_bounds__(256) void k_node_update(
    const float* __restrict__ h, const float* __restrict__ accum,
    const float* __restrict__ wl_g, float* __restrict__ out)
{
    int lane = threadIdx.x & 63;
    int col  = lane & 15;
    int quad = lane >> 4;
    int wid  = blockIdx.x * 4 + (threadIdx.x >> 6);
    int nwaves = gridDim.x * 4;

    bf16x8 bfr[5][4];
    #pragma unroll
    for (int kc = 0; kc < 5; ++kc)
        #pragma unroll
        for (int nt = 0; nt < 4; ++nt) {
            #pragma unroll
            for (int j = 0; j < 8; ++j) {
                int k = kc * 32 + quad * 8 + j;
                bfr[kc][nt][j] = f2bf(wl_g[k * 64 + nt * 16 + col]);
            }
        }

    for (int tile = wid; tile < NHB; tile += nwaves) {
        int n = tile * 16 + col;
        f32x4 acc[4];
        #pragma unroll
        for (int nt = 0; nt < 4; ++nt) acc[nt] = (f32x4){0.f, 0.f, 0.f, 0.f};

        #pragma unroll
        for (int kc = 0; kc < 5; ++kc) {
            int kbase = kc * 32 + quad * 8;
            const float* p = (kbase < 64)
                ? (h     + (size_t)n * 64 + kbase)
                : (accum + (size_t)n * 96 + (kbase - 64));
            float4 va = *(const float4*)p;
            float4 vb = *(const float4*)(p + 4);
            bf16x8 af;
            af[0] = f2bf(va.x); af[1] = f2bf(va.y);
            af[2] = f2bf(va.z); af[3] = f2bf(va.w);
            af[4] = f2bf(vb.x); af[5] = f2bf(vb.y);
            af[6] = f2bf(vb.z); af[7] = f2bf(vb.w);
            #pragma unroll
            for (int nt = 0; nt < 4; ++nt)
                acc[nt] = __builtin_amdgcn_mfma_f32_16x16x32_bf16(
                    af, bfr[kc][nt], acc[nt], 0, 0, 0);
        }

        #pragma unroll
        for (int nt = 0; nt < 4; ++nt) {
            #pragma unroll
            for (int r = 0; r < 4; ++r) {
                int node = tile * 16 + quad * 4 + r;
                out[(size_t)node * 64 + nt * 16 + col] = fmaxf(acc[nt][r], 0.f);
            }
        }
    }
}

// ---------------------------------------------------------------------------
// Workspace layout (4-byte words):
//   [0, 2NN)            dp      (float2 {den_src, p3}; zeroed)
//   [2NN, 3NN)          cnt     (int, zeroed)
//   [3NN, 3NN+16)       gtotal  (int, zeroed)
//   [3NN+16, 4NN+16)    off     (int)
//   [4NN+16, 5NN+16)    p1      (float)
//   [5NN+16, 6NN+16)    pd      (float)
//   [6NN+16, +4NE)      recA    (int4; byte off 1200064 %16==0)
//   [6NN+16+4NE, ...)   Z: au (float2, 2NE) + rank (int, NE) -- dead after
//                          k_edge; accum (float, 96NN) aliases Z (96NN > 3NE)
// total = 6NN+16 + 4NE + 96NN words ≈ 33.2 MB
// ---------------------------------------------------------------------------
extern "C" void kernel_launch(void* const* d_in, const int* in_sizes, int n_in,
                              void* d_out, int out_size, void* d_ws, size_t ws_size,
                              hipStream_t stream)
{
    const float* h   = (const float*)d_in[0];
    const float* ef  = (const float*)d_in[1];
    const int*   src = (const int*)d_in[2];
    const int*   dst = (const int*)d_in[3];
    const float* wg  = (const float*)d_in[4];
    const float* wa  = (const float*)d_in[5];
    const float* wl  = (const float*)d_in[6];
    float* out = (float*)d_out;

    float* ws = (float*)d_ws;
    float*  dpf    = ws;                       // float2 view at same addr
    int*    cnt    = (int*)(ws + 2 * NN);
    int*    gtotal = (int*)(ws + 3 * NN);
    int*    off    = (int*)(ws + 3 * NN + 16);
    float*  p1     = ws + 4 * NN + 16;
    float*  pd     = ws + 5 * NN + 16;
    int4*   recA   = (int4*)(ws + 6 * NN + 16);
    float2* au     = (float2*)(ws + 6 * NN + 16 + 4 * NE);
    int*    rank   = (int*)(ws + 6 * NN + 16 + 4 * NE + 2 * NE);
    float*  accum  = ws + 6 * NN + 16 + 4 * NE;   // aliases au/rank (dead)

    hipMemsetAsync(d_ws, 0, (size_t)(3 * NN + 16) * sizeof(float), stream);

    k_pre<<<3 * NHB, 256, 0, stream>>>(h, ef, dst, wg, wa, cnt, rank, p1, pd,
                                       dpf, au);
    k_assign<<<(NN + 255) / 256, 256, 0, stream>>>(cnt, off, gtotal);
    k_edge<<<NHB, 256, 0, stream>>>(au, src, dst, rank, p1, pd, dpf, off, recA);
    k_rewrite<<<NHB, 256, 0, stream>>>((const float2*)dpf, recA);
    k_reduce<<<NN / 4, 256, 0, stream>>>(h, ef, cnt, off, recA, accum);
    k_node_update<<<256, 256, 0, stream>>>(h, accum, wl, out);
}